// Round 2
// baseline (3811.094 us; speedup 1.0000x reference)
//
#include <hip/hip_runtime.h>

typedef unsigned short u16;
typedef __attribute__((ext_vector_type(8))) short bf16x8;
typedef __attribute__((ext_vector_type(4))) float f32x4;
typedef __attribute__((ext_vector_type(4))) unsigned short u16x4;

#define QN    2048
#define BSZ   128
#define TMAXK 128
#define STEPF 0.01f
#define NEWTON_ITERS 46

__device__ __forceinline__ u16 f2bf(float f){
  unsigned u = __float_as_uint(f);
  u += 0x7fffu + ((u >> 16) & 1u);          // round-to-nearest-even
  return (u16)(u >> 16);
}
__device__ __forceinline__ float bf2f(u16 h){
  return __uint_as_float(((unsigned)h) << 16);
}

// ============================ preprocessing ============================

// alpha[q] = ||P_q||_1 * ||P_q||_inf  >= sigma_max(P_q)^2
__global__ __launch_bounds__(256) void alpha_k(const float* __restrict__ P, float* __restrict__ alpha){
  int q = blockIdx.x, i = threadIdx.x;
  const float* Pb = P + (size_t)(q << 8) * QN + (q << 8);
  float rs = 0.f, cs = 0.f;
  for (int c = 0; c < 256; ++c){
    rs += fabsf(Pb[(size_t)i * QN + c]);
    cs += fabsf(Pb[(size_t)c * QN + i]);
  }
  __shared__ float red[256];
  red[i] = rs; __syncthreads();
  for (int o = 128; o > 0; o >>= 1){ if (i < o) red[i] = fmaxf(red[i], red[i+o]); __syncthreads(); }
  float mr = red[0];
  __syncthreads();
  red[i] = cs; __syncthreads();
  for (int o = 128; o > 0; o >>= 1){ if (i < o) red[i] = fmaxf(red[i], red[i+o]); __syncthreads(); }
  if (i == 0) alpha[q] = mr * red[0];
}

// V0 = P_q^T / alpha[q]   (V stored as 8 contiguous 256x256 row-major)
__global__ __launch_bounds__(256) void initV_k(const float* __restrict__ P, const float* __restrict__ alpha, float* __restrict__ V){
  int idx = blockIdx.x * 256 + threadIdx.x;       // 8*65536 total
  int q = idx >> 16, rc = idx & 65535;
  int r = rc >> 8, c = rc & 255;
  V[idx] = P[(size_t)((q << 8) + c) * QN + (q << 8) + r] / alpha[q];
}

// T[q] = P_q @ V[q]   (256x256x256, 64x64 tiles, 4x4 micro)
__global__ __launch_bounds__(256) void newton_T_k(const float* __restrict__ P, const float* __restrict__ Vin, float* __restrict__ Tm){
  int q = blockIdx.x >> 4;
  int tl = blockIdx.x & 15;
  int rb = (tl >> 2) << 6, cb = (tl & 3) << 6;
  const float* Ab = P + (size_t)(q << 8) * QN + (q << 8);   // lda = QN
  const float* Bb = Vin + (q << 16);                        // ldb = 256
  __shared__ float Asm[16][68];
  __shared__ float Bsm[16][68];
  int tid = threadIdx.x, ty = tid >> 4, tx = tid & 15;
  float acc[4][4];
#pragma unroll
  for (int i = 0; i < 4; i++)
#pragma unroll
    for (int j = 0; j < 4; j++) acc[i][j] = 0.f;
  int ar = tid >> 2, ak = (tid & 3) << 2;
  int bc = tid & 63, bk = tid >> 6;
  for (int kb = 0; kb < 256; kb += 16){
    f32x4 av = *(const f32x4*)(Ab + (size_t)(rb + ar) * QN + kb + ak);
    float b0 = Bb[(size_t)(kb + bk     ) * 256 + cb + bc];
    float b1 = Bb[(size_t)(kb + bk +  4) * 256 + cb + bc];
    float b2 = Bb[(size_t)(kb + bk +  8) * 256 + cb + bc];
    float b3 = Bb[(size_t)(kb + bk + 12) * 256 + cb + bc];
    __syncthreads();
    Asm[ak+0][ar] = av.x; Asm[ak+1][ar] = av.y; Asm[ak+2][ar] = av.z; Asm[ak+3][ar] = av.w;
    Bsm[bk   ][bc] = b0;  Bsm[bk+ 4][bc] = b1;  Bsm[bk+ 8][bc] = b2;  Bsm[bk+12][bc] = b3;
    __syncthreads();
#pragma unroll
    for (int kk = 0; kk < 16; kk++){
      f32x4 a = *(const f32x4*)&Asm[kk][ty << 2];
      f32x4 b = *(const f32x4*)&Bsm[kk][tx << 2];
#pragma unroll
      for (int i = 0; i < 4; i++)
#pragma unroll
        for (int j = 0; j < 4; j++) acc[i][j] += a[i] * b[j];
    }
  }
  float* Ob = Tm + (q << 16);
#pragma unroll
  for (int i = 0; i < 4; i++){
    f32x4 o; o.x = acc[i][0]; o.y = acc[i][1]; o.z = acc[i][2]; o.w = acc[i][3];
    *(f32x4*)(Ob + (size_t)(rb + (ty << 2) + i) * 256 + cb + (tx << 2)) = o;
  }
}

// Vout[q] = 2*Vin[q] - Vin[q] @ T[q]
__global__ __launch_bounds__(256) void newton_V_k(const float* __restrict__ Vin, const float* __restrict__ Tm, float* __restrict__ Vout){
  int q = blockIdx.x >> 4;
  int tl = blockIdx.x & 15;
  int rb = (tl >> 2) << 6, cb = (tl & 3) << 6;
  const float* Ab = Vin + (q << 16);   // lda = 256
  const float* Bb = Tm + (q << 16);    // ldb = 256
  __shared__ float Asm[16][68];
  __shared__ float Bsm[16][68];
  int tid = threadIdx.x, ty = tid >> 4, tx = tid & 15;
  float acc[4][4];
#pragma unroll
  for (int i = 0; i < 4; i++)
#pragma unroll
    for (int j = 0; j < 4; j++) acc[i][j] = 0.f;
  int ar = tid >> 2, ak = (tid & 3) << 2;
  int bc = tid & 63, bk = tid >> 6;
  for (int kb = 0; kb < 256; kb += 16){
    f32x4 av = *(const f32x4*)(Ab + (size_t)(rb + ar) * 256 + kb + ak);
    float b0 = Bb[(size_t)(kb + bk     ) * 256 + cb + bc];
    float b1 = Bb[(size_t)(kb + bk +  4) * 256 + cb + bc];
    float b2 = Bb[(size_t)(kb + bk +  8) * 256 + cb + bc];
    float b3 = Bb[(size_t)(kb + bk + 12) * 256 + cb + bc];
    __syncthreads();
    Asm[ak+0][ar] = av.x; Asm[ak+1][ar] = av.y; Asm[ak+2][ar] = av.z; Asm[ak+3][ar] = av.w;
    Bsm[bk   ][bc] = b0;  Bsm[bk+ 4][bc] = b1;  Bsm[bk+ 8][bc] = b2;  Bsm[bk+12][bc] = b3;
    __syncthreads();
#pragma unroll
    for (int kk = 0; kk < 16; kk++){
      f32x4 a = *(const f32x4*)&Asm[kk][ty << 2];
      f32x4 b = *(const f32x4*)&Bsm[kk][tx << 2];
#pragma unroll
      for (int i = 0; i < 4; i++)
#pragma unroll
        for (int j = 0; j < 4; j++) acc[i][j] += a[i] * b[j];
    }
  }
  float* Ob = Vout + (q << 16);
#pragma unroll
  for (int i = 0; i < 4; i++){
    f32x4 vo = *(const f32x4*)(Ab + (size_t)(rb + (ty << 2) + i) * 256 + cb + (tx << 2));
    f32x4 o;
    o.x = 2.f*vo.x - acc[i][0]; o.y = 2.f*vo.y - acc[i][1];
    o.z = 2.f*vo.z - acc[i][2]; o.w = 2.f*vo.w - acc[i][3];
    *(f32x4*)(Ob + (size_t)(rb + (ty << 2) + i) * 256 + cb + (tx << 2)) = o;
  }
}

// Ymat[:, Bj] = Wm[Bj,:]^T @ P_j  ; Wm masked (zero iff block(row)==block(col of W))
__global__ __launch_bounds__(256) void build_Y_k(const float* __restrict__ W, const float* __restrict__ P, float* __restrict__ Ymat){
  int j  = blockIdx.x >> 7;
  int rt = (blockIdx.x >> 2) & 31;
  int ct = blockIdx.x & 3;
  int rb = rt << 6, cb = ct << 6, jb = j << 8;
  int tid = threadIdx.x, ty = tid >> 4, tx = tid & 15;
  if ((rt >> 2) == j){              // whole A-panel masked to zero -> tile is zero
#pragma unroll
    for (int i = 0; i < 4; i++){
      f32x4 z = {0.f, 0.f, 0.f, 0.f};
      *(f32x4*)(Ymat + (size_t)(rb + (ty << 2) + i) * QN + jb + cb + (tx << 2)) = z;
    }
    return;
  }
  __shared__ float Asm[16][68];
  __shared__ float Bsm[16][68];
  float acc[4][4];
#pragma unroll
  for (int i = 0; i < 4; i++)
#pragma unroll
    for (int j2 = 0; j2 < 4; j2++) acc[i][j2] = 0.f;
  int sr = tid & 63, sk = tid >> 6;
  for (int kb = 0; kb < 256; kb += 16){
    float a0 = W[(size_t)(jb + kb + sk     ) * QN + rb + sr];
    float a1 = W[(size_t)(jb + kb + sk +  4) * QN + rb + sr];
    float a2 = W[(size_t)(jb + kb + sk +  8) * QN + rb + sr];
    float a3 = W[(size_t)(jb + kb + sk + 12) * QN + rb + sr];
    float b0 = P[(size_t)(jb + kb + sk     ) * QN + jb + cb + sr];
    float b1 = P[(size_t)(jb + kb + sk +  4) * QN + jb + cb + sr];
    float b2 = P[(size_t)(jb + kb + sk +  8) * QN + jb + cb + sr];
    float b3 = P[(size_t)(jb + kb + sk + 12) * QN + jb + cb + sr];
    __syncthreads();
    Asm[sk   ][sr] = a0; Asm[sk+ 4][sr] = a1; Asm[sk+ 8][sr] = a2; Asm[sk+12][sr] = a3;
    Bsm[sk   ][sr] = b0; Bsm[sk+ 4][sr] = b1; Bsm[sk+ 8][sr] = b2; Bsm[sk+12][sr] = b3;
    __syncthreads();
#pragma unroll
    for (int kk = 0; kk < 16; kk++){
      f32x4 a = *(const f32x4*)&Asm[kk][ty << 2];
      f32x4 b = *(const f32x4*)&Bsm[kk][tx << 2];
#pragma unroll
      for (int i = 0; i < 4; i++)
#pragma unroll
        for (int j2 = 0; j2 < 4; j2++) acc[i][j2] += a[i] * b[j2];
    }
  }
#pragma unroll
  for (int i = 0; i < 4; i++){
    f32x4 o; o.x = acc[i][0]; o.y = acc[i][1]; o.z = acc[i][2]; o.w = acc[i][3];
    *(f32x4*)(Ymat + (size_t)(rb + (ty << 2) + i) * QN + jb + cb + (tx << 2)) = o;
  }
}

// Z[Bi,:] = V_i @ Ymat[Bi,:];  M = A + Wm - Z; write bf16 hi/lo into C1/C2 (cols 0..2047)
__global__ __launch_bounds__(256) void build_C_k(const float* __restrict__ Vfin, const float* __restrict__ Ymat,
                                                 const float* __restrict__ Ain, const float* __restrict__ W,
                                                 u16* __restrict__ C1, u16* __restrict__ C2){
  int ib = blockIdx.x >> 7;
  int rest = blockIdx.x & 127;
  int rt = rest >> 5, ct = rest & 31;
  int rb = rt << 6, cb = ct << 6;
  const float* Ab = Vfin + (ib << 16);  // lda 256
  __shared__ float Asm[16][68];
  __shared__ float Bsm[16][68];
  int tid = threadIdx.x, ty = tid >> 4, tx = tid & 15;
  float acc[4][4];
#pragma unroll
  for (int i = 0; i < 4; i++)
#pragma unroll
    for (int j = 0; j < 4; j++) acc[i][j] = 0.f;
  int ar = tid >> 2, ak = (tid & 3) << 2;
  int bc = tid & 63, bk = tid >> 6;
  for (int kb = 0; kb < 256; kb += 16){
    f32x4 av = *(const f32x4*)(Ab + (size_t)(rb + ar) * 256 + kb + ak);
    float b0 = Ymat[(size_t)((ib << 8) + kb + bk     ) * QN + cb + bc];
    float b1 = Ymat[(size_t)((ib << 8) + kb + bk +  4) * QN + cb + bc];
    float b2 = Ymat[(size_t)((ib << 8) + kb + bk +  8) * QN + cb + bc];
    float b3 = Ymat[(size_t)((ib << 8) + kb + bk + 12) * QN + cb + bc];
    __syncthreads();
    Asm[ak+0][ar] = av.x; Asm[ak+1][ar] = av.y; Asm[ak+2][ar] = av.z; Asm[ak+3][ar] = av.w;
    Bsm[bk   ][bc] = b0;  Bsm[bk+ 4][bc] = b1;  Bsm[bk+ 8][bc] = b2;  Bsm[bk+12][bc] = b3;
    __syncthreads();
#pragma unroll
    for (int kk = 0; kk < 16; kk++){
      f32x4 a = *(const f32x4*)&Asm[kk][ty << 2];
      f32x4 b = *(const f32x4*)&Bsm[kk][tx << 2];
#pragma unroll
      for (int i = 0; i < 4; i++)
#pragma unroll
        for (int j = 0; j < 4; j++) acc[i][j] += a[i] * b[j];
    }
  }
#pragma unroll
  for (int i = 0; i < 4; i++){
    int row = (ib << 8) + rb + (ty << 2) + i;
#pragma unroll
    for (int j = 0; j < 4; j++){
      int col = cb + (tx << 2) + j;
      float wv = ((row >> 8) == (col >> 8)) ? 0.f : W[(size_t)row * QN + col];
      float m = Ain[(size_t)row * QN + col] + wv - acc[i][j];
      u16 hi = f2bf(m);
      u16 lo = f2bf(m - bf2f(hi));
      C1[((size_t)row << 12) + col] = hi;
      C2[((size_t)row << 12) + col] = lo;
    }
  }
}

// B matrix -> bf16 hi/lo into C1/C2 (cols 2048..4095)
__global__ __launch_bounds__(256) void split_B_k(const float* __restrict__ Bin, u16* __restrict__ C1, u16* __restrict__ C2){
  int idx = blockIdx.x * 256 + threadIdx.x;  // 2048*2048
  int r = idx >> 11, c = idx & 2047;
  float v = Bin[idx];
  u16 hi = f2bf(v);
  u16 lo = f2bf(v - bf2f(hi));
  C1[((size_t)r << 12) + 2048 + c] = hi;
  C2[((size_t)r << 12) + 2048 + c] = lo;
}

// Xf[bs][qn] = X0; Yst = [bf16(X) | bf16(relu X)]; out[:,0,:] = X0
__global__ __launch_bounds__(256) void init_state_k(const float* __restrict__ X0, float* __restrict__ Xf,
                                                    u16* __restrict__ Yst, float* __restrict__ out){
  int idx = blockIdx.x * 256 + threadIdx.x;  // 128*2048
  int bs = idx >> 11, qn = idx & 2047;
  float x = X0[idx];
  Xf[idx] = x;
  Yst[((size_t)bs << 12) + qn] = f2bf(x);
  Yst[((size_t)bs << 12) + 2048 + qn] = f2bf(fmaxf(x, 0.f));
  out[((size_t)bs * TMAXK) * QN + qn] = x;
}

// ============================ main loop ============================

// Split-K partial GEMM: U_partial[s] = C1[:,ks]*Y[ks] + C2[:,ks]*Y[ks]
// grid 512 = 32 rowgroups (64 rows) x 16 k-slices (256); 256 thr = 4 waves (32 cols each)
__global__ __launch_bounds__(256) void step_gemm_k(const u16* __restrict__ C1, const u16* __restrict__ C2,
                                                   const u16* __restrict__ Yst, float* __restrict__ part){
  __shared__ __align__(16) char lds[65536];  // [2 panels][64 rows][256 k] bf16, XOR-swizzled
  int tid = threadIdx.x;
  int rg = blockIdx.x >> 4, s = blockIdx.x & 15;
  int k0 = s << 8;
  // stage both C-panels (reg->LDS so we can swizzle; global_load_lds can't)
  for (int ro = 0; ro < 16; ++ro){
    int e = ro * 256 + tid;                 // [0,4096): 8 bf16 each
    const u16* src = (e < 2048) ? C1 : C2;
    int el = e & 2047;
    int r = el >> 5;                        // 0..63
    int k8 = (el & 31) << 3;                // 0..248
    bf16x8 v = *(const bf16x8*)(src + ((size_t)((rg << 6) + r) << 12) + k0 + k8);
    int addr = ((e >> 11) << 15) + ((((r << 9) + (k8 << 1))) ^ ((r & 7) << 4));
    *(bf16x8*)(lds + addr) = v;
  }
  __syncthreads();
  int w = tid >> 6, l = tid & 63;
  int lo16 = l & 15, hi = l >> 4;
  f32x4 acc[4][2];
#pragma unroll
  for (int m = 0; m < 4; m++)
#pragma unroll
    for (int n = 0; n < 2; n++){ acc[m][n].x = 0.f; acc[m][n].y = 0.f; acc[m][n].z = 0.f; acc[m][n].w = 0.f; }
  const u16* yb = Yst + ((size_t)((w << 5) + lo16) << 12) + k0 + (hi << 3);
#pragma unroll
  for (int ks = 0; ks < 8; ++ks){
    bf16x8 b0 = *(const bf16x8*)(yb + ks * 32);
    bf16x8 b1 = *(const bf16x8*)(yb + 65536 + ks * 32);   // +16 bs rows
    int kb2 = (ks * 32 + (hi << 3)) << 1;
#pragma unroll
    for (int m = 0; m < 4; m++){
      int row = (m << 4) + lo16;
      int ba = ((row << 9) + kb2) ^ ((row & 7) << 4);
      bf16x8 a1 = *(const bf16x8*)(lds + ba);
      bf16x8 a2 = *(const bf16x8*)(lds + 32768 + ba);
      acc[m][0] = __builtin_amdgcn_mfma_f32_16x16x32_bf16(a1, b0, acc[m][0], 0, 0, 0);
      acc[m][0] = __builtin_amdgcn_mfma_f32_16x16x32_bf16(a2, b0, acc[m][0], 0, 0, 0);
      acc[m][1] = __builtin_amdgcn_mfma_f32_16x16x32_bf16(a1, b1, acc[m][1], 0, 0, 0);
      acc[m][1] = __builtin_amdgcn_mfma_f32_16x16x32_bf16(a2, b1, acc[m][1], 0, 0, 0);
    }
  }
  // partial[s][bs][row], f32x4 along row (C/D frag: col=lane&15, row=(lane>>4)*4+reg)
#pragma unroll
  for (int m = 0; m < 4; m++)
#pragma unroll
    for (int n = 0; n < 2; n++){
      int bs = (w << 5) + (n << 4) + lo16;
      int row = (rg << 6) + (m << 4) + (hi << 2);
      *(f32x4*)(part + ((size_t)(s * BSZ + bs) << 11) + row) = acc[m][n];
    }
}

// Reduce partials, X += STEP*(U + b), emit out[:,t,:] and next bf16 Y state
__global__ __launch_bounds__(256) void step_update_k(const float* __restrict__ part, float* __restrict__ Xf,
                                                     const float* __restrict__ bx, u16* __restrict__ Yst,
                                                     float* __restrict__ out, int t){
  int tid = blockIdx.x * 256 + threadIdx.x;   // 65536 threads x 4 elems
  int bs = tid >> 9;
  int row = (tid & 511) << 2;
  size_t base = ((size_t)bs << 11) + row;
  f32x4 u = {0.f, 0.f, 0.f, 0.f};
#pragma unroll
  for (int s = 0; s < 16; s++){
    f32x4 p = *(const f32x4*)(part + ((size_t)s << 18) + base);
    u += p;
  }
  f32x4 x = *(const f32x4*)(Xf + base);
  f32x4 b = *(const f32x4*)(bx + row);
  f32x4 xn = x + STEPF * (u + b);
  *(f32x4*)(Xf + base) = xn;
  *(f32x4*)(out + ((size_t)(bs * TMAXK + t) << 11) + row) = xn;
  u16x4 hv, rv;
  hv.x = f2bf(xn.x); hv.y = f2bf(xn.y); hv.z = f2bf(xn.z); hv.w = f2bf(xn.w);
  rv.x = f2bf(fmaxf(xn.x, 0.f)); rv.y = f2bf(fmaxf(xn.y, 0.f));
  rv.z = f2bf(fmaxf(xn.z, 0.f)); rv.w = f2bf(fmaxf(xn.w, 0.f));
  *(u16x4*)(Yst + ((size_t)bs << 12) + row) = hv;
  *(u16x4*)(Yst + ((size_t)bs << 12) + 2048 + row) = rv;
}

// ============================ host ============================

extern "C" void kernel_launch(void* const* d_in, const int* in_sizes, int n_in,
                              void* d_out, int out_size, void* d_ws, size_t ws_size,
                              hipStream_t stream){
  (void)in_sizes; (void)n_in; (void)out_size; (void)ws_size;
  const float* X0  = (const float*)d_in[0];
  const float* Ain = (const float*)d_in[1];
  const float* Bin = (const float*)d_in[2];
  const float* Win = (const float*)d_in[3];
  const float* Pin = (const float*)d_in[4];
  const float* bx  = (const float*)d_in[5];
  float* out = (float*)d_out;
  char* ws = (char*)d_ws;
  const size_t MB = 1u << 20;

  u16*   C1    = (u16*)(ws);               // 16 MB [2048][4096] bf16 = [Mh|Bh]
  u16*   C2    = (u16*)(ws + 16*MB);       // 16 MB [Ml|Bl]
  float* Xf    = (float*)(ws + 32*MB);     // 1 MB  [128][2048] f32 state
  u16*   Yst   = (u16*)(ws + 33*MB);       // 1 MB  [128][4096] bf16 [X|relu X]
  float* Ymat  = (float*)(ws + 34*MB);     // 16 MB (preproc)  -- aliased with:
  float* part  = (float*)(ws + 34*MB);     // 16 MB [16][128][2048] f32 partials (main loop)
  float* Vb0   = (float*)(ws + 50*MB);     // 2 MB  8x256x256
  float* Vb1   = (float*)(ws + 52*MB);     // 2 MB
  float* Tm    = (float*)(ws + 54*MB);     // 2 MB
  float* alpha = (float*)(ws + 56*MB);     // 32 B

  // --- preprocessing: blockwise P^-1 via Newton-Schulz ---
  alpha_k<<<8, 256, 0, stream>>>(Pin, alpha);
  initV_k<<<2048, 256, 0, stream>>>(Pin, alpha, Vb0);
  float* Vc = Vb0; float* Vo = Vb1;
  for (int it = 0; it < NEWTON_ITERS; ++it){
    newton_T_k<<<128, 256, 0, stream>>>(Pin, Vc, Tm);
    newton_V_k<<<128, 256, 0, stream>>>(Vc, Tm, Vo);
    float* tmp = Vc; Vc = Vo; Vo = tmp;
  }
  // --- M = A + Wm - P^-1 Wm^T P, split to bf16 hi/lo; B split too ---
  build_Y_k<<<1024, 256, 0, stream>>>(Win, Pin, Ymat);
  build_C_k<<<1024, 256, 0, stream>>>(Vc, Ymat, Ain, Win, C1, C2);
  split_B_k<<<16384, 256, 0, stream>>>(Bin, C1, C2);
  init_state_k<<<1024, 256, 0, stream>>>(X0, Xf, Yst, out);

  // --- 127 sequential steps ---
  for (int t = 1; t < TMAXK; ++t){
    step_gemm_k<<<512, 256, 0, stream>>>(C1, C2, Yst, part);
    step_update_k<<<256, 256, 0, stream>>>(part, Xf, bx, Yst, out, t);
  }
}